// Round 15
// baseline (306.303 us; speedup 1.0000x reference)
//
#include <hip/hip_runtime.h>
#include <hip/hip_bf16.h>
#include <stdint.h>

#define B_ 8
#define NH_ 12
#define NBH (B_*NH_)       // 96
#define T_ 1024
#define D_ 256

typedef __attribute__((ext_vector_type(8))) short bf16x8;
typedef __attribute__((ext_vector_type(16))) float f32x16;
typedef unsigned short ushort_t;

#define Z16 ((f32x16){0,0,0,0,0,0,0,0,0,0,0,0,0,0,0,0})

// KR pre-scale: 0.25 * sqrt(log2(e)) so that (KR.KR^T) = (S/sqrt(256)) * log2(e)
#define KSCALE 0.30028060218f

__device__ __forceinline__ short f2bf(float x) {
  __hip_bfloat16 h = __float2bfloat16(x);
  return *reinterpret_cast<short*>(&h);
}
__device__ __forceinline__ float bf2f(short x) {
  unsigned int u = ((unsigned int)(unsigned short)x) << 16;
  return __uint_as_float(u);
}
__device__ __forceinline__ void gload16(const ushort_t* g, ushort_t* l) {
  __builtin_amdgcn_global_load_lds(
      (const __attribute__((address_space(1))) uint32_t*)g,
      (__attribute__((address_space(3))) uint32_t*)l, 16, 0, 0);
}

// ---------------- prep kernels (unchanged, proven) ----------------

__global__ void tab_kernel(const float* __restrict__ freqs, float2* __restrict__ tab) {
  int idx = blockIdx.x * blockDim.x + threadIdx.x;
  if (idx >= T_ * (D_/2)) return;
  int t = idx >> 7;
  int i = idx & 127;
  float ph = (float)t * freqs[2*i];
  ph -= floorf(ph);
  float ang = ph * 6.283185307179586f;
  tab[idx] = make_float2(cosf(ang), sinf(ang));
}

__global__ __launch_bounds__(256) void kr_kernel(const float* __restrict__ Q,
                                                 const float2* __restrict__ tab,
                                                 ushort_t* __restrict__ KR) {
  int row = blockIdx.x * 8 + (threadIdx.x >> 5);
  int d8  = threadIdx.x & 31;
  int t = row & (T_ - 1);
  const float* src = Q + (size_t)row * D_ + d8 * 8;
  float4 x0 = *(const float4*)src;
  float4 x1 = *(const float4*)(src + 4);
  const float2* tr = tab + t * (D_/2) + d8 * 4;
  float2 c0 = tr[0], c1 = tr[1], c2 = tr[2], c3 = tr[3];
  bf16x8 f;
  f[0] = f2bf((x0.x * c0.x - x0.y * c0.y) * KSCALE);
  f[1] = f2bf((x0.y * c0.x + x0.x * c0.y) * KSCALE);
  f[2] = f2bf((x0.z * c1.x - x0.w * c1.y) * KSCALE);
  f[3] = f2bf((x0.w * c1.x + x0.z * c1.y) * KSCALE);
  f[4] = f2bf((x1.x * c2.x - x1.y * c2.y) * KSCALE);
  f[5] = f2bf((x1.y * c2.x + x1.x * c2.y) * KSCALE);
  f[6] = f2bf((x1.z * c3.x - x1.w * c3.y) * KSCALE);
  f[7] = f2bf((x1.w * c3.x + x1.z * c3.y) * KSCALE);
  *(bf16x8*)(KR + (size_t)row * D_ + d8 * 8) = f;
}

__global__ __launch_bounds__(256) void vt_kernel(const float* __restrict__ V,
                                                 ushort_t* __restrict__ VT) {
  int blk = blockIdx.x;
  int d64 = blk & 3, t64 = (blk >> 2) & 15, bh = blk >> 6;
  __shared__ ushort_t st[64][66];
  {
    int t = threadIdx.x >> 2, j = threadIdx.x & 3;
    const float* src = V + ((size_t)bh * T_ + t64 * 64 + t) * D_ + d64 * 64 + j * 16;
#pragma unroll
    for (int q2 = 0; q2 < 4; ++q2) {
      float4 x = *(const float4*)(src + q2 * 4);
      st[t][j*16 + q2*4 + 0] = (ushort_t)f2bf(x.x);
      st[t][j*16 + q2*4 + 1] = (ushort_t)f2bf(x.y);
      st[t][j*16 + q2*4 + 2] = (ushort_t)f2bf(x.z);
      st[t][j*16 + q2*4 + 3] = (ushort_t)f2bf(x.w);
    }
  }
  __syncthreads();
  {
    int d = threadIdx.x >> 2, tq = threadIdx.x & 3;
    bf16x8 a_, b_;
#pragma unroll
    for (int i = 0; i < 8; ++i) {
      a_[i] = (short)st[tq*16 + i][d];
      b_[i] = (short)st[tq*16 + 8 + i][d];
    }
    ushort_t* dst = VT + ((size_t)bh * D_ + d64*64 + d) * T_ + t64*64 + tq*16;
    *(bf16x8*)dst = a_;
    *(bf16x8*)(dst + 8) = b_;
  }
}

// ---------------- GEMM1: P = exp2(KR . KR^T), symmetric (r9/r12-EXACT) -------
__global__ __launch_bounds__(256, 4)
void gemm1_kernel(const ushort_t* __restrict__ KRg, ushort_t* __restrict__ P) {
  int bid = blockIdx.x;
  int nblk = gridDim.x;                       // nh*36, divisible by 8
  int swz = (bid & 7) * (nblk >> 3) + (bid >> 3);
  int b = swz % 36;
  int h = swz / 36;
  int ti = (int)((sqrtf(8.0f * b + 1.0f) - 1.0f) * 0.5f);
  int si = b - ti * (ti + 1) / 2;

  const ushort_t* __restrict__ Kh = KRg + (size_t)h * (T_ * D_);
  ushort_t* __restrict__ Ph = P + (size_t)h * (T_ * T_);

  const int tid = threadIdx.x, lane = tid & 63, wv = tid >> 6;
  const int lo = lane & 31, hi = lane >> 5;

  __shared__ __align__(16) ushort_t SH[2 * 128 * 64];   // At | Bt (32 KB)
  ushort_t* At = SH;
  ushort_t* Bt = SH + 128 * 64;

  f32x16 acc[4];
#pragma unroll
  for (int j = 0; j < 4; ++j) acc[j] = Z16;

  const ushort_t* Abase = Kh + (size_t)ti * 128 * D_;
  const ushort_t* Bbase = Kh + (size_t)si * 128 * D_;

  for (int ks = 0; ks < 4; ++ks) {
    int k0 = ks * 64;
    __syncthreads();                 // WAR: previous compute done
#pragma unroll
    for (int i = 0; i < 4; ++i) {
      int d = tid + i * 256;         // chunk index 0..1023
      int r = d >> 3, c = d & 7;
      int srcoff = r * D_ + k0 + ((c ^ (r & 7)) * 8);
      gload16(Abase + srcoff, &At[d * 8]);
      gload16(Bbase + srcoff, &Bt[d * 8]);
    }
    __syncthreads();                 // RAW (includes vmcnt drain)
    __builtin_amdgcn_s_setprio(1);
#pragma unroll
    for (int kk = 0; kk < 4; ++kk) {
      int ra = 32 * wv + lo;
      bf16x8 af = *(const bf16x8*)&At[ra * 64 + (((2*kk + hi) ^ (ra & 7)) * 8)];
#pragma unroll
      for (int j = 0; j < 4; ++j) {
        int rb = 32 * j + lo;
        bf16x8 bf_ = *(const bf16x8*)&Bt[rb * 64 + (((2*kk + hi) ^ (rb & 7)) * 8)];
        acc[j] = __builtin_amdgcn_mfma_f32_32x32x16_bf16(af, bf_, acc[j], 0, 0, 0);
      }
    }
    __builtin_amdgcn_s_setprio(0);
  }

  // epilogue: pe = bf16(exp2(acc)); write normal tile (t row, s col)
  ushort_t pe[4][16];
#pragma unroll
  for (int j = 0; j < 4; ++j)
#pragma unroll
    for (int r = 0; r < 16; ++r)
      pe[j][r] = (ushort_t)f2bf(exp2f(acc[j][r]));

#pragma unroll
  for (int j = 0; j < 4; ++j) {
#pragma unroll
    for (int r = 0; r < 16; ++r) {
      int t = ti * 128 + 32 * wv + ((r & 3) + 8 * (r >> 2) + 4 * hi);
      int s = si * 128 + 32 * j + lo;
      Ph[(size_t)t * T_ + s] = pe[j][r];
    }
  }

  if (ti != si) {
    __syncthreads();   // all waves done with At/Bt MFMA reads
    ushort_t* Lt = SH; // 32 KB = [128][128] bf16
#pragma unroll
    for (int j = 0; j < 4; ++j) {
#pragma unroll
      for (int r = 0; r < 16; ++r) {
        int trow = 32 * wv + ((r & 3) + 8 * (r >> 2) + 4 * hi);
        int scol = 32 * j + lo;
        int cc = (trow >> 3) ^ (scol & 7);
        Lt[scol * 128 + (cc << 3) + (trow & 7)] = pe[j][r];
      }
    }
    __syncthreads();
#pragma unroll
    for (int it = 0; it < 8; ++it) {
      int sr = it * 16 + (tid >> 4);
      int c  = tid & 15;
      bf16x8 vv = *(const bf16x8*)&Lt[sr * 128 + ((c ^ (sr & 7)) << 3)];
      *(bf16x8*)&Ph[(size_t)(si * 128 + sr) * T_ + ti * 128 + c * 8] = vv;
    }
  }
}

// ---------------- GEMM2: O = (P . V) / rowsum(P)  (per head) ----------------
// di=1: block = 128t x 256d (FULL d-width) -> each P byte staged exactly once
// (P staging traffic halves vs r12). Wave owns 32t x 256d, acc[8] (128 AGPR).
// r9-exact single-buffer sync structure; LDS 48 KB -> 3 blocks/CU.
// l[t] accumulated from the same bf16 P fragments the MFMA consumes.
__global__ __launch_bounds__(256, 3)
void gemm2_kernel(const ushort_t* __restrict__ P, const ushort_t* __restrict__ VTg,
                  float* __restrict__ Og) {
  int bid = blockIdx.x;
  int nblk = gridDim.x;                       // nh*8, divisible by 8
  int swz = (bid & 7) * (nblk >> 3) + (bid >> 3);
  int ti = swz & 7;
  int h  = swz >> 3;

  const ushort_t* __restrict__ Ph = P + (size_t)h * (T_ * T_);
  const ushort_t* __restrict__ Vh = VTg + (size_t)h * (D_ * T_);
  float* __restrict__ Oh = Og + (size_t)h * (T_ * D_);

  const int tid = threadIdx.x, lane = tid & 63, wv = tid >> 6;
  const int lo = lane & 31, hi = lane >> 5;

  __shared__ __align__(16) ushort_t At[128 * 64];   // P t-rows tile (16 KB)
  __shared__ __align__(16) ushort_t Bt[256 * 64];   // VT d-rows tile (32 KB)
  __shared__ float lB[4][32];

  f32x16 acc[8];
#pragma unroll
  for (int j = 0; j < 8; ++j) acc[j] = Z16;
  float lsum = 0.0f;

  const ushort_t* Abase = Ph + (size_t)ti * 128 * T_;
  const ushort_t* Bbase = Vh;                       // full 256 d-rows

  for (int ks = 0; ks < 16; ++ks) {
    int k0 = ks * 64;
    __syncthreads();                 // WAR: previous compute done
    // stage At: 1024 chunks (4/thread), Bt: 2048 chunks (8/thread)
#pragma unroll
    for (int i = 0; i < 4; ++i) {
      int d = tid + i * 256;
      int r = d >> 3, c = d & 7;
      gload16(Abase + r * T_ + k0 + ((c ^ (r & 7)) * 8), &At[d * 8]);
    }
#pragma unroll
    for (int i = 0; i < 8; ++i) {
      int d = tid + i * 256;
      int r = d >> 3, c = d & 7;
      gload16(Bbase + r * T_ + k0 + ((c ^ (r & 7)) * 8), &Bt[d * 8]);
    }
    __syncthreads();                 // RAW (includes vmcnt drain)
    __builtin_amdgcn_s_setprio(1);
#pragma unroll
    for (int kk = 0; kk < 4; ++kk) {
      int ra = 32 * wv + lo;
      bf16x8 pf = *(const bf16x8*)&At[ra * 64 + (((2*kk + hi) ^ (ra & 7)) * 8)];
      float s01 = bf2f(pf[0]) + bf2f(pf[1]);
      float s23 = bf2f(pf[2]) + bf2f(pf[3]);
      float s45 = bf2f(pf[4]) + bf2f(pf[5]);
      float s67 = bf2f(pf[6]) + bf2f(pf[7]);
      lsum += (s01 + s23) + (s45 + s67);
#pragma unroll
      for (int j = 0; j < 8; ++j) {
        int rb = 32 * j + lo;
        bf16x8 vf = *(const bf16x8*)&Bt[rb * 64 + (((2*kk + hi) ^ (rb & 7)) * 8)];
        acc[j] = __builtin_amdgcn_mfma_f32_32x32x16_bf16(pf, vf, acc[j], 0, 0, 0);
      }
    }
    __builtin_amdgcn_s_setprio(0);
  }

  // full row-sum: combine the two hi-halves (lane ^ 32 holds the other half)
  lsum += __shfl_xor(lsum, 32);
  if (hi == 0) lB[wv][lo] = lsum;   // row t = ti*128 + 32wv + lo
  asm volatile("s_waitcnt lgkmcnt(0)" ::: "memory");

  // epilogue: O[t][d] = acc / l[t];  32 lanes x 4B contiguous per (j,r)
#pragma unroll
  for (int r = 0; r < 16; ++r) {
    int crow = (r & 3) + 8 * (r >> 2) + 4 * hi;
    float inv = 1.0f / lB[wv][crow];
    int t = ti * 128 + 32 * wv + crow;
#pragma unroll
    for (int j = 0; j < 8; ++j) {
      Oh[(size_t)t * D_ + 32 * j + lo] = acc[j][r] * inv;
    }
  }
}

extern "C" void kernel_launch(void* const* d_in, const int* in_sizes, int n_in,
                              void* d_out, int out_size, void* d_ws, size_t ws_size,
                              hipStream_t stream) {
  const float* Q     = (const float*)d_in[0];
  const float* V     = (const float*)d_in[1];
  const float* freqs = (const float*)d_in[2];
  float* Out = (float*)d_out;

  // ws layout: tab 1MB | KR 48MB | VT 48MB | P (96 or 192 MB)
  float2* tab  = (float2*)d_ws;
  ushort_t* KR = (ushort_t*)((char*)d_ws + (1 << 20));
  ushort_t* VT = (ushort_t*)((char*)d_ws + (1 << 20) + (size_t)NBH * T_ * D_ * 2);
  ushort_t* P  = (ushort_t*)((char*)d_ws + (1 << 20) + (size_t)2 * NBH * T_ * D_ * 2);

  tab_kernel<<<(T_ * (D_/2) + 255) / 256, 256, 0, stream>>>(freqs, tab);
  kr_kernel<<<NBH * T_ / 8, 256, 0, stream>>>(Q, tab, KR);
  vt_kernel<<<NBH * 16 * 4, 256, 0, stream>>>(V, VT);

  size_t base = (1 << 20) + (size_t)2 * NBH * T_ * D_ * 2;       // 97 MB
  size_t need1 = base + (size_t)NBH * T_ * T_ * 2;               // +192 MB
  int ng = (ws_size >= need1) ? 1 : 2;                           // fall back to 2 groups
  int hg = NBH / ng;

  for (int g = 0; g < ng; ++g) {
    const ushort_t* KRg = KR + (size_t)g * hg * T_ * D_;
    const ushort_t* VTg = VT + (size_t)g * hg * D_ * T_;
    float* Og = Out + (size_t)g * hg * T_ * D_;
    gemm1_kernel<<<hg * 36, 256, 0, stream>>>(KRg, P);
    gemm2_kernel<<<hg * 8, 256, 0, stream>>>(P, VTg, Og);
  }
}

// Round 16
// 233.264 us; speedup vs baseline: 1.3131x; 1.3131x over previous
//
#include <hip/hip_runtime.h>
#include <hip/hip_bf16.h>
#include <stdint.h>

#define B_ 8
#define NH_ 12
#define NBH (B_*NH_)       // 96
#define T_ 1024
#define D_ 256

typedef __attribute__((ext_vector_type(8))) short bf16x8;
typedef __attribute__((ext_vector_type(16))) float f32x16;
typedef unsigned short ushort_t;

#define Z16 ((f32x16){0,0,0,0,0,0,0,0,0,0,0,0,0,0,0,0})

// KR pre-scale: 0.25 * sqrt(log2(e)) so that (KR.KR^T) = (S/sqrt(256)) * log2(e)
#define KSCALE 0.30028060218f

__device__ __forceinline__ short f2bf(float x) {
  __hip_bfloat16 h = __float2bfloat16(x);
  return *reinterpret_cast<short*>(&h);
}
__device__ __forceinline__ float bf2f(short x) {
  unsigned int u = ((unsigned int)(unsigned short)x) << 16;
  return __uint_as_float(u);
}
__device__ __forceinline__ void gload16(const ushort_t* g, ushort_t* l) {
  __builtin_amdgcn_global_load_lds(
      (const __attribute__((address_space(1))) uint32_t*)g,
      (__attribute__((address_space(3))) uint32_t*)l, 16, 0, 0);
}

// ---------------- prep kernels (unchanged, proven) ----------------

__global__ void tab_kernel(const float* __restrict__ freqs, float2* __restrict__ tab) {
  int idx = blockIdx.x * blockDim.x + threadIdx.x;
  if (idx >= T_ * (D_/2)) return;
  int t = idx >> 7;
  int i = idx & 127;
  float ph = (float)t * freqs[2*i];
  ph -= floorf(ph);
  float ang = ph * 6.283185307179586f;
  tab[idx] = make_float2(cosf(ang), sinf(ang));
}

__global__ __launch_bounds__(256) void kr_kernel(const float* __restrict__ Q,
                                                 const float2* __restrict__ tab,
                                                 ushort_t* __restrict__ KR) {
  int row = blockIdx.x * 8 + (threadIdx.x >> 5);
  int d8  = threadIdx.x & 31;
  int t = row & (T_ - 1);
  const float* src = Q + (size_t)row * D_ + d8 * 8;
  float4 x0 = *(const float4*)src;
  float4 x1 = *(const float4*)(src + 4);
  const float2* tr = tab + t * (D_/2) + d8 * 4;
  float2 c0 = tr[0], c1 = tr[1], c2 = tr[2], c3 = tr[3];
  bf16x8 f;
  f[0] = f2bf((x0.x * c0.x - x0.y * c0.y) * KSCALE);
  f[1] = f2bf((x0.y * c0.x + x0.x * c0.y) * KSCALE);
  f[2] = f2bf((x0.z * c1.x - x0.w * c1.y) * KSCALE);
  f[3] = f2bf((x0.w * c1.x + x0.z * c1.y) * KSCALE);
  f[4] = f2bf((x1.x * c2.x - x1.y * c2.y) * KSCALE);
  f[5] = f2bf((x1.y * c2.x + x1.x * c2.y) * KSCALE);
  f[6] = f2bf((x1.z * c3.x - x1.w * c3.y) * KSCALE);
  f[7] = f2bf((x1.w * c3.x + x1.z * c3.y) * KSCALE);
  *(bf16x8*)(KR + (size_t)row * D_ + d8 * 8) = f;
}

__global__ __launch_bounds__(256) void vt_kernel(const float* __restrict__ V,
                                                 ushort_t* __restrict__ VT) {
  int blk = blockIdx.x;
  int d64 = blk & 3, t64 = (blk >> 2) & 15, bh = blk >> 6;
  __shared__ ushort_t st[64][66];
  {
    int t = threadIdx.x >> 2, j = threadIdx.x & 3;
    const float* src = V + ((size_t)bh * T_ + t64 * 64 + t) * D_ + d64 * 64 + j * 16;
#pragma unroll
    for (int q2 = 0; q2 < 4; ++q2) {
      float4 x = *(const float4*)(src + q2 * 4);
      st[t][j*16 + q2*4 + 0] = (ushort_t)f2bf(x.x);
      st[t][j*16 + q2*4 + 1] = (ushort_t)f2bf(x.y);
      st[t][j*16 + q2*4 + 2] = (ushort_t)f2bf(x.z);
      st[t][j*16 + q2*4 + 3] = (ushort_t)f2bf(x.w);
    }
  }
  __syncthreads();
  {
    int d = threadIdx.x >> 2, tq = threadIdx.x & 3;
    bf16x8 a_, b_;
#pragma unroll
    for (int i = 0; i < 8; ++i) {
      a_[i] = (short)st[tq*16 + i][d];
      b_[i] = (short)st[tq*16 + 8 + i][d];
    }
    ushort_t* dst = VT + ((size_t)bh * D_ + d64*64 + d) * T_ + t64*64 + tq*16;
    *(bf16x8*)dst = a_;
    *(bf16x8*)(dst + 8) = b_;
  }
}

// ---------------- GEMM1: P = exp2(KR . KR^T), symmetric (r9-EXACT) ----------
__global__ __launch_bounds__(256, 4)
void gemm1_kernel(const ushort_t* __restrict__ KRg, ushort_t* __restrict__ P) {
  int bid = blockIdx.x;
  int nblk = gridDim.x;                       // nh*36, divisible by 8
  int swz = (bid & 7) * (nblk >> 3) + (bid >> 3);
  int b = swz % 36;
  int h = swz / 36;
  int ti = (int)((sqrtf(8.0f * b + 1.0f) - 1.0f) * 0.5f);
  int si = b - ti * (ti + 1) / 2;

  const ushort_t* __restrict__ Kh = KRg + (size_t)h * (T_ * D_);
  ushort_t* __restrict__ Ph = P + (size_t)h * (T_ * T_);

  const int tid = threadIdx.x, lane = tid & 63, wv = tid >> 6;
  const int lo = lane & 31, hi = lane >> 5;

  __shared__ __align__(16) ushort_t SH[2 * 128 * 64];   // At | Bt (32 KB)
  ushort_t* At = SH;
  ushort_t* Bt = SH + 128 * 64;

  f32x16 acc[4];
#pragma unroll
  for (int j = 0; j < 4; ++j) acc[j] = Z16;

  const ushort_t* Abase = Kh + (size_t)ti * 128 * D_;
  const ushort_t* Bbase = Kh + (size_t)si * 128 * D_;

  for (int ks = 0; ks < 4; ++ks) {
    int k0 = ks * 64;
    __syncthreads();                 // WAR: previous compute done
#pragma unroll
    for (int i = 0; i < 4; ++i) {
      int d = tid + i * 256;         // chunk index 0..1023
      int r = d >> 3, c = d & 7;
      int srcoff = r * D_ + k0 + ((c ^ (r & 7)) * 8);
      gload16(Abase + srcoff, &At[d * 8]);
      gload16(Bbase + srcoff, &Bt[d * 8]);
    }
    __syncthreads();                 // RAW (includes vmcnt drain)
    __builtin_amdgcn_s_setprio(1);
#pragma unroll
    for (int kk = 0; kk < 4; ++kk) {
      int ra = 32 * wv + lo;
      bf16x8 af = *(const bf16x8*)&At[ra * 64 + (((2*kk + hi) ^ (ra & 7)) * 8)];
#pragma unroll
      for (int j = 0; j < 4; ++j) {
        int rb = 32 * j + lo;
        bf16x8 bf_ = *(const bf16x8*)&Bt[rb * 64 + (((2*kk + hi) ^ (rb & 7)) * 8)];
        acc[j] = __builtin_amdgcn_mfma_f32_32x32x16_bf16(af, bf_, acc[j], 0, 0, 0);
      }
    }
    __builtin_amdgcn_s_setprio(0);
  }

  // epilogue: pe = bf16(exp2(acc)); write normal tile (t row, s col)
  ushort_t pe[4][16];
#pragma unroll
  for (int j = 0; j < 4; ++j)
#pragma unroll
    for (int r = 0; r < 16; ++r)
      pe[j][r] = (ushort_t)f2bf(exp2f(acc[j][r]));

#pragma unroll
  for (int j = 0; j < 4; ++j) {
#pragma unroll
    for (int r = 0; r < 16; ++r) {
      int t = ti * 128 + 32 * wv + ((r & 3) + 8 * (r >> 2) + 4 * hi);
      int s = si * 128 + 32 * j + lo;
      Ph[(size_t)t * T_ + s] = pe[j][r];
    }
  }

  if (ti != si) {
    __syncthreads();   // all waves done with At/Bt MFMA reads
    ushort_t* Lt = SH; // 32 KB = [128][128] bf16
#pragma unroll
    for (int j = 0; j < 4; ++j) {
#pragma unroll
      for (int r = 0; r < 16; ++r) {
        int trow = 32 * wv + ((r & 3) + 8 * (r >> 2) + 4 * hi);
        int scol = 32 * j + lo;
        int cc = (trow >> 3) ^ (scol & 7);
        Lt[scol * 128 + (cc << 3) + (trow & 7)] = pe[j][r];
      }
    }
    __syncthreads();
#pragma unroll
    for (int it = 0; it < 8; ++it) {
      int sr = it * 16 + (tid >> 4);
      int c  = tid & 15;
      bf16x8 vv = *(const bf16x8*)&Lt[sr * 128 + ((c ^ (sr & 7)) << 3)];
      *(bf16x8*)&Ph[(size_t)(si * 128 + sr) * T_ + ti * 128 + c * 8] = vv;
    }
  }
}

// ---------------- GEMM2: O = (P . V) / rowsum(P)  (r12-EXACT) ----------------
// Double-buffered in the r3 idiom: separate named shared arrays swapped via
// macro args; per k-step: stage(next -> PN/VN), compute(PC/VC), single
// __syncthreads (implicit vmcnt drain completes the stage). l[t] accumulated
// from the same bf16 P fragments the MFMA consumes.
#define G2_STAGE(KS, PD, VD)                                                   \
  {                                                                            \
    int k0_ = (KS) * 64;                                                       \
    _Pragma("unroll")                                                          \
    for (int i = 0; i < 4; ++i) {                                              \
      int dd = tid + i * 256;                                                  \
      int r = dd >> 3, c = dd & 7;                                             \
      int off_ = r * T_ + k0_ + ((c ^ (r & 7)) * 8);                           \
      gload16(Abase + off_, &PD[dd * 8]);                                      \
      gload16(Bbase + off_, &VD[dd * 8]);                                      \
    }                                                                          \
  }

#define G2_ITER(TT, PC, VC, PN, VN)                                            \
  {                                                                            \
    if ((TT) + 1 < 16) G2_STAGE((TT) + 1, PN, VN);                             \
    __builtin_amdgcn_s_setprio(1);                                             \
    _Pragma("unroll")                                                          \
    for (int kk = 0; kk < 4; ++kk) {                                           \
      int ra = 32 * wv + lo;                                                   \
      bf16x8 pf = *(const bf16x8*)&PC[ra * 64 + (((2*kk + hi) ^ (ra & 7)) * 8)]; \
      float s01 = bf2f(pf[0]) + bf2f(pf[1]);                                   \
      float s23 = bf2f(pf[2]) + bf2f(pf[3]);                                   \
      float s45 = bf2f(pf[4]) + bf2f(pf[5]);                                   \
      float s67 = bf2f(pf[6]) + bf2f(pf[7]);                                   \
      lsum += (s01 + s23) + (s45 + s67);                                       \
      _Pragma("unroll")                                                        \
      for (int j = 0; j < 4; ++j) {                                            \
        int rb = 32 * j + lo;                                                  \
        bf16x8 vf = *(const bf16x8*)&VC[rb * 64 + (((2*kk + hi) ^ (rb & 7)) * 8)]; \
        acc[j] = __builtin_amdgcn_mfma_f32_32x32x16_bf16(pf, vf, acc[j], 0, 0, 0); \
      }                                                                        \
    }                                                                          \
    __builtin_amdgcn_s_setprio(0);                                             \
    __syncthreads();                                                           \
  }

__global__ __launch_bounds__(256, 2)
void gemm2_kernel(const ushort_t* __restrict__ P, const ushort_t* __restrict__ VTg,
                  float* __restrict__ Og) {
  int bid = blockIdx.x;
  int nblk = gridDim.x;                       // nh*16, divisible by 8
  int swz = (bid & 7) * (nblk >> 3) + (bid >> 3);
  int di = swz & 1;
  int ti = (swz >> 1) & 7;
  int h  = swz >> 4;

  const ushort_t* __restrict__ Ph = P + (size_t)h * (T_ * T_);
  const ushort_t* __restrict__ Vh = VTg + (size_t)h * (D_ * T_);
  float* __restrict__ Oh = Og + (size_t)h * (T_ * D_);

  const int tid = threadIdx.x, lane = tid & 63, wv = tid >> 6;
  const int lo = lane & 31, hi = lane >> 5;

  __shared__ __align__(16) ushort_t Pa[128 * 64];
  __shared__ __align__(16) ushort_t Pb[128 * 64];
  __shared__ __align__(16) ushort_t Va[128 * 64];
  __shared__ __align__(16) ushort_t Vb[128 * 64];
  __shared__ float lB[4][32];

  f32x16 acc[4];
#pragma unroll
  for (int j = 0; j < 4; ++j) acc[j] = Z16;
  float lsum = 0.0f;

  const ushort_t* Abase = Ph + (size_t)ti * 128 * T_;
  const ushort_t* Bbase = Vh + (size_t)di * 128 * T_;

  // prologue: stage tile 0 into Pa/Va
  G2_STAGE(0, Pa, Va);
  __syncthreads();

  for (int t2 = 0; t2 < 16; t2 += 2) {
    G2_ITER(t2,     Pa, Va, Pb, Vb);
    G2_ITER(t2 + 1, Pb, Vb, Pa, Va);
  }

  // full row-sum: combine the two hi-halves (lane ^ 32 holds the other half)
  lsum += __shfl_xor(lsum, 32);
  if (hi == 0) lB[wv][lo] = lsum;   // row t = ti*128 + 32wv + lo
  asm volatile("s_waitcnt lgkmcnt(0)" ::: "memory");

  // epilogue: O[t][d] = acc / l[t];  32 lanes x 4B contiguous per (j,r)
#pragma unroll
  for (int r = 0; r < 16; ++r) {
    int crow = (r & 3) + 8 * (r >> 2) + 4 * hi;
    float inv = 1.0f / lB[wv][crow];
    int t = ti * 128 + 32 * wv + crow;
#pragma unroll
    for (int j = 0; j < 4; ++j) {
      Oh[(size_t)t * D_ + di * 128 + 32 * j + lo] = acc[j][r] * inv;
    }
  }
}

extern "C" void kernel_launch(void* const* d_in, const int* in_sizes, int n_in,
                              void* d_out, int out_size, void* d_ws, size_t ws_size,
                              hipStream_t stream) {
  const float* Q     = (const float*)d_in[0];
  const float* V     = (const float*)d_in[1];
  const float* freqs = (const float*)d_in[2];
  float* Out = (float*)d_out;

  // ws layout: tab 1MB | KR 48MB | VT 48MB | P (96 or 192 MB)
  float2* tab  = (float2*)d_ws;
  ushort_t* KR = (ushort_t*)((char*)d_ws + (1 << 20));
  ushort_t* VT = (ushort_t*)((char*)d_ws + (1 << 20) + (size_t)NBH * T_ * D_ * 2);
  ushort_t* P  = (ushort_t*)((char*)d_ws + (1 << 20) + (size_t)2 * NBH * T_ * D_ * 2);

  tab_kernel<<<(T_ * (D_/2) + 255) / 256, 256, 0, stream>>>(freqs, tab);
  kr_kernel<<<NBH * T_ / 8, 256, 0, stream>>>(Q, tab, KR);
  vt_kernel<<<NBH * 16 * 4, 256, 0, stream>>>(V, VT);

  size_t base = (1 << 20) + (size_t)2 * NBH * T_ * D_ * 2;       // 97 MB
  size_t need1 = base + (size_t)NBH * T_ * T_ * 2;               // +192 MB
  int ng = (ws_size >= need1) ? 1 : 2;                           // fall back to 2 groups
  int hg = NBH / ng;

  for (int g = 0; g < ng; ++g) {
    const ushort_t* KRg = KR + (size_t)g * hg * T_ * D_;
    const ushort_t* VTg = VT + (size_t)g * hg * D_ * T_;
    float* Og = Out + (size_t)g * hg * T_ * D_;
    gemm1_kernel<<<hg * 36, 256, 0, stream>>>(KRg, P);
    gemm2_kernel<<<hg * 16, 256, 0, stream>>>(P, VTg, Og);
  }
}